// Round 11
// baseline (631.972 us; speedup 1.0000x reference)
//
#include <hip/hip_runtime.h>

typedef __bf16 bf16x8 __attribute__((ext_vector_type(8)));
typedef __bf16 bf16x4 __attribute__((ext_vector_type(4)));
typedef short short4v __attribute__((ext_vector_type(4)));
typedef float f32x4 __attribute__((ext_vector_type(4)));

__device__ __forceinline__ f32x4 mfma16(bf16x8 a, bf16x8 b, f32x4 c) {
  return __builtin_amdgcn_mfma_f32_16x16x32_bf16(a, b, c, 0, 0, 0);
}

// K=16 MFMA: C/D layout == B-operand layout -> S^T frags feed PV directly.
__device__ __forceinline__ f32x4 mfma16k16(bf16x4 a, bf16x4 b, f32x4 c) {
#if __has_builtin(__builtin_amdgcn_mfma_f32_16x16x16bf16_1k)
  short4v as = __builtin_bit_cast(short4v, a);
  short4v bs = __builtin_bit_cast(short4v, b);
  return __builtin_amdgcn_mfma_f32_16x16x16bf16_1k(as, bs, c, 0, 0, 0);
#else
  f32x4 d;
  asm volatile("v_mfma_f32_16x16x16_bf16 %0, %1, %2, %3"
               : "=v"(d)
               : "v"(a), "v"(b), "v"(c));
  return d;
#endif
}

__device__ __forceinline__ float fast_exp2(float x) {
  return __builtin_amdgcn_exp2f(x);  // v_exp_f32 (native exp2)
}

typedef const __attribute__((address_space(1))) void gvoid_t;
typedef __attribute__((address_space(3))) void svoid_t;
__device__ __forceinline__ void lds16(const __bf16* g, __bf16* l) {
  // async 16B/lane global->LDS; dest = wave-uniform base + lane*16
  __builtin_amdgcn_global_load_lds((gvoid_t*)g, (svoid_t*)l, 16, 0, 0);
}

// ------- fused fp32 -> bf16 convert of all inputs (+ mask bias table) -------
__global__ __launch_bounds__(256) void prep(const float* __restrict__ hidden,
                                            const float* __restrict__ Wq,
                                            const float* __restrict__ Wk,
                                            const float* __restrict__ Wv,
                                            const float* __restrict__ Wo,
                                            const int* __restrict__ amask,
                                            __bf16* __restrict__ hb,
                                            __bf16* __restrict__ Wqkvb,
                                            __bf16* __restrict__ Wob,
                                            float* __restrict__ maskb) {
  int idx = blockIdx.x * 256 + threadIdx.x;
  if (idx < 1024) {  // mask bias: 0 -> -1.5e9, 1 -> -16 (static softmax max)
    int4 m = *(const int4*)(amask + idx * 4);
    float4 mb = { m.x ? -16.0f : -1.5e9f, m.y ? -16.0f : -1.5e9f,
                  m.z ? -16.0f : -1.5e9f, m.w ? -16.0f : -1.5e9f };
    *(float4*)(maskb + idx * 4) = mb;
  }
  int q = idx;
  const float* src;
  __bf16* dst;
  if (q < 1048576) {
    src = hidden; dst = hb;
  } else if ((q -= 1048576) < 262144) {
    src = Wq; dst = Wqkvb;
  } else if ((q -= 262144) < 65536) {
    src = Wk; dst = Wqkvb + 1048576;
  } else if ((q -= 65536) < 65536) {
    src = Wv; dst = Wqkvb + 1310720;
  } else {
    q -= 65536;
    src = Wo; dst = Wob;
  }
  float4 v = *(const float4*)(src + (size_t)q * 4);
  bf16x4 o = { (__bf16)v.x, (__bf16)v.y, (__bf16)v.z, (__bf16)v.w };
  *(bf16x4*)(dst + (size_t)q * 4) = o;
}

// ------ QKV GEMM (128x128, lds16 dbuf) with fused RoPE / V-transpose --------
// N=1536. Epilogue: Q/K quadrants get RoPE applied to f32 acc (pairs are
// (acc[i][0],acc[i][1]) and (acc[i][2],acc[i][3]) at d=l16); V quadrants
// write VT[(b*256 + vc)*2048 + s] instead of QKV.
__global__ __launch_bounds__(256) void gemm_qkv(const __bf16* __restrict__ A,
                                                const __bf16* __restrict__ B,
                                                __bf16* __restrict__ QKV,
                                                __bf16* __restrict__ VT) {
  __shared__ __bf16 As[2][128][32];
  __shared__ __bf16 Bs[2][128][32];
  const int m0 = blockIdx.x * 128, n0 = blockIdx.y * 128;
  const int tid = threadIdx.x;
  const int wave = tid >> 6, lane = tid & 63, quad = lane >> 4, l16 = lane & 15;
  const int wr = wave >> 1, wc = wave & 1;
  const int srow = 32 * wave;
  const __bf16* Ag = A + (size_t)(m0 + srow + (lane >> 2)) * 1024 + (lane & 3) * 8;
  const __bf16* Bg = B + (size_t)(n0 + srow + (lane >> 2)) * 1024 + (lane & 3) * 8;
  f32x4 acc[4][4] = {};

  auto stage = [&](int buf, int k0) {
    lds16(Ag + k0, &As[buf][srow][0]);
    lds16(Ag + 16 * 1024 + k0, &As[buf][srow + 16][0]);
    lds16(Bg + k0, &Bs[buf][srow][0]);
    lds16(Bg + 16 * 1024 + k0, &Bs[buf][srow + 16][0]);
  };
  stage(0, 0);
  __syncthreads();
  int buf = 0;
  for (int k0 = 0; k0 < 1024; k0 += 32) {
    if (k0 + 32 < 1024) stage(buf ^ 1, k0 + 32);
    bf16x8 af[4], bfr[4];
#pragma unroll
    for (int i = 0; i < 4; i++)
      af[i] = *(bf16x8*)&As[buf][64 * wr + 16 * i + l16][quad * 8];
#pragma unroll
    for (int j = 0; j < 4; j++)
      bfr[j] = *(bf16x8*)&Bs[buf][64 * wc + 16 * j + l16][quad * 8];
#pragma unroll
    for (int i = 0; i < 4; i++)
#pragma unroll
      for (int j = 0; j < 4; j++) acc[i][j] = mfma16(af[i], bfr[j], acc[i][j]);
    __syncthreads();
    buf ^= 1;
  }
  const int colbase = n0 + 64 * wc;  // wave-uniform; 64-aligned = 2 heads
  if (colbase < 1280) {
    // ---- Q or K quadrant: RoPE on f32 accumulators, then store ----
    float invf = __expf(-(float)l16 * 0.5756462732485114f);  // 10000^(-l16/16)
#pragma unroll
    for (int i = 0; i < 4; i++)
#pragma unroll
      for (int r = 0; r < 4; r++) {
        int row = m0 + 64 * wr + 16 * i + quad * 4 + r;
        float ang = (float)(row & 2047) * invf;
        float sn, cs;
        __sincosf(ang, &sn, &cs);
        float x0 = acc[i][0][r], x1 = acc[i][1][r];
        acc[i][0][r] = x0 * cs - x1 * sn;
        acc[i][1][r] = x1 * cs + x0 * sn;
        float y0 = acc[i][2][r], y1 = acc[i][3][r];
        acc[i][2][r] = y0 * cs - y1 * sn;
        acc[i][3][r] = y1 * cs + y0 * sn;
      }
#pragma unroll
    for (int i = 0; i < 4; i++)
#pragma unroll
      for (int j = 0; j < 4; j++)
#pragma unroll
        for (int r = 0; r < 4; r++) {
          int row = m0 + 64 * wr + 16 * i + quad * 4 + r;
          int col = colbase + 16 * j + l16;
          QKV[(size_t)row * 1536 + col] = (__bf16)acc[i][j][r];
        }
  } else {
    // ---- V quadrant: write transposed VT[(b*256+vc)*2048 + s] ----
#pragma unroll
    for (int i = 0; i < 4; i++)
#pragma unroll
      for (int j = 0; j < 4; j++)
#pragma unroll
        for (int r = 0; r < 4; r++) {
          int row = m0 + 64 * wr + 16 * i + quad * 4 + r;
          int vc = colbase + 16 * j + l16 - 1280;
          int b_ = row >> 11, s = row & 2047;
          VT[((size_t)(b_ * 256 + vc)) * 2048 + s] = (__bf16)acc[i][j][r];
        }
  }
}

// ------ Wo GEMM: plain 128x128 lds16 dbuf, f32 out ------
__global__ __launch_bounds__(256) void gemm_out(const __bf16* __restrict__ A,
                                                const __bf16* __restrict__ B,
                                                float* __restrict__ C) {
  __shared__ __bf16 As[2][128][32];
  __shared__ __bf16 Bs[2][128][32];
  const int m0 = blockIdx.x * 128, n0 = blockIdx.y * 128;
  const int tid = threadIdx.x;
  const int wave = tid >> 6, lane = tid & 63, quad = lane >> 4, l16 = lane & 15;
  const int wr = wave >> 1, wc = wave & 1;
  const int srow = 32 * wave;
  const __bf16* Ag = A + (size_t)(m0 + srow + (lane >> 2)) * 1024 + (lane & 3) * 8;
  const __bf16* Bg = B + (size_t)(n0 + srow + (lane >> 2)) * 1024 + (lane & 3) * 8;
  f32x4 acc[4][4] = {};

  auto stage = [&](int buf, int k0) {
    lds16(Ag + k0, &As[buf][srow][0]);
    lds16(Ag + 16 * 1024 + k0, &As[buf][srow + 16][0]);
    lds16(Bg + k0, &Bs[buf][srow][0]);
    lds16(Bg + 16 * 1024 + k0, &Bs[buf][srow + 16][0]);
  };
  stage(0, 0);
  __syncthreads();
  int buf = 0;
  for (int k0 = 0; k0 < 1024; k0 += 32) {
    if (k0 + 32 < 1024) stage(buf ^ 1, k0 + 32);
    bf16x8 af[4], bfr[4];
#pragma unroll
    for (int i = 0; i < 4; i++)
      af[i] = *(bf16x8*)&As[buf][64 * wr + 16 * i + l16][quad * 8];
#pragma unroll
    for (int j = 0; j < 4; j++)
      bfr[j] = *(bf16x8*)&Bs[buf][64 * wc + 16 * j + l16][quad * 8];
#pragma unroll
    for (int i = 0; i < 4; i++)
#pragma unroll
      for (int j = 0; j < 4; j++) acc[i][j] = mfma16(af[i], bfr[j], acc[i][j]);
    __syncthreads();
    buf ^= 1;
  }
#pragma unroll
  for (int i = 0; i < 4; i++)
#pragma unroll
    for (int j = 0; j < 4; j++)
#pragma unroll
      for (int r = 0; r < 4; r++) {
        int row = m0 + 64 * wr + 16 * i + quad * 4 + r;
        int col = n0 + 64 * wc + 16 * j + l16;
        C[(size_t)row * 1024 + col] = acc[i][j][r];
      }
}

// ------- Flash attention, split-K partials + in-kernel combine --------------
// Block (xp, z): strips {xp, 15-xp}; z halves the key range (uniform 17
// tiles/block). After a strip's partials land, the second-arriving z block
// (device-scope atomic flag) normalizes that strip into Ob.
__global__ __launch_bounds__(256, 4) void attn(const __bf16* __restrict__ QKV,
                                               const __bf16* __restrict__ VT,
                                               const float* __restrict__ maskb,
                                               __bf16* __restrict__ Opart,
                                               float* __restrict__ rspart,
                                               __bf16* __restrict__ Ob,
                                               int* __restrict__ flags) {
  __shared__ __bf16 Ks[2][64][40];
  __shared__ __bf16 Vs[2][32][72];
  __shared__ int flag_sh;
  const int tid = threadIdx.x;
  const int wave = tid >> 6, lane = tid & 63;
  const int quad = lane >> 4, l16 = lane & 15;
  const int b = blockIdx.z, h = blockIdx.y, hkv = h >> 2;
  const int xp = blockIdx.x >> 1, z = blockIdx.x & 1;
  const float SC2 = 0.25503472f;  // (1/sqrt(32)) * log2(e)

  const int sk_key = tid >> 2, sk_ch = (tid & 3) * 8;
  const int sv_d = tid >> 3, sv_seg = (tid & 7) * 8;
  const __bf16* ksrc = QKV + (size_t)(b * 2048 + sk_key) * 1536 + 1024 + hkv * 32 + sk_ch;
  const __bf16* vsrc = VT + ((size_t)(b * 8 + hkv) * 32 + sv_d) * 2048 + sv_seg;
  const float* mrow = maskb + b * 2048;

  for (int sp = 0; sp < 2; sp++) {
    const int strip = sp ? 15 - xp : xp;
    const int t_begin = z ? (strip + 1) : 0;
    const int t_end = z ? (2 * strip + 2) : (strip + 1);
    const int qw = strip * 128 + wave * 32;
    const int q_row0 = qw + l16, q_row1 = qw + 16 + l16;
    const __bf16* qbase = QKV + (size_t)(b * 2048 + qw + l16) * 1536 + h * 32 + quad * 8;
    bf16x8 qf0 = *(const bf16x8*)qbase;
    bf16x8 qf1 = *(const bf16x8*)(qbase + 16 * 1536);

    {  // stage tile t_begin into buffer 0
      uint4 kr = *(const uint4*)(ksrc + (size_t)t_begin * 64 * 1536);
      uint4 vr = *(const uint4*)(vsrc + (size_t)t_begin * 64);
      *(uint4*)&Ks[0][sk_key][sk_ch] = kr;
      *(uint4*)&Vs[0][sv_d][sv_seg] = vr;
    }
    __syncthreads();

    f32x4 o00 = {}, o01 = {}, o10 = {}, o11 = {};
    float rs0 = 0.f, rs1 = 0.f;
    int buf = 0;

    for (int t = t_begin; t < t_end; t++) {
      const int kv0 = t << 6;
      const bool more = (t + 1 < t_end);
      uint4 kr, vr;
      if (more) {
        kr = *(const uint4*)(ksrc + (size_t)(t + 1) * 64 * 1536);
        vr = *(const uint4*)(vsrc + (size_t)(t + 1) * 64);
      }
      if (kv0 <= qw + 31) {  // wave-uniform: any visible key?
        bf16x8 kf[4];
#pragma unroll
        for (int kt = 0; kt < 4; kt++)
          kf[kt] = *(bf16x8*)&Ks[buf][16 * kt + l16][quad * 8];
        f32x4 s0[4], s1[4];
#pragma unroll
        for (int kt = 0; kt < 4; kt++) {
          f32x4 zz = {};
          s0[kt] = mfma16(kf[kt], qf0, zz);
          s1[kt] = mfma16(kf[kt], qf1, zz);
        }
        // ---- static-max softmax -> packed B-operands (registers only) ----
        bf16x4 pb0[4], pb1[4];
        if (kv0 + 63 <= qw) {  // full tile
#pragma unroll
          for (int kt = 0; kt < 4; kt++) {
            const int kb = kv0 + 16 * kt + 4 * quad;
            float4 mb = *(const float4*)(mrow + kb);
#pragma unroll
            for (int r = 0; r < 4; r++) {
              float e0 = fast_exp2(fmaf(s0[kt][r], SC2, (&mb.x)[r]));
              float e1 = fast_exp2(fmaf(s1[kt][r], SC2, (&mb.x)[r]));
              rs0 += e0;
              rs1 += e1;
              pb0[kt][r] = (__bf16)e0;
              pb1[kt][r] = (__bf16)e1;
            }
          }
        } else {  // diagonal tile
#pragma unroll
          for (int kt = 0; kt < 4; kt++) {
            const int kb = kv0 + 16 * kt + 4 * quad;
            float4 mb = *(const float4*)(mrow + kb);
#pragma unroll
            for (int r = 0; r < 4; r++) {
              const int key = kb + r;
              float e0 = fast_exp2(fmaf(s0[kt][r], SC2, (&mb.x)[r]));
              float e1 = fast_exp2(fmaf(s1[kt][r], SC2, (&mb.x)[r]));
              e0 = (key <= q_row0) ? e0 : 0.f;
              e1 = (key <= q_row1) ? e1 : 0.f;
              rs0 += e0;
              rs1 += e1;
              pb0[kt][r] = (__bf16)e0;
              pb1[kt][r] = (__bf16)e1;
            }
          }
        }
        // ---- PV via K=16 MFMA: A = V^T frags (8B LDS reads), B = pb regs ---
#pragma unroll
        for (int kt = 0; kt < 4; kt++) {
          bf16x4 v0 = *(bf16x4*)&Vs[buf][l16][16 * kt + 4 * quad];
          bf16x4 v1 = *(bf16x4*)&Vs[buf][16 + l16][16 * kt + 4 * quad];
          o00 = mfma16k16(v0, pb0[kt], o00);
          o01 = mfma16k16(v1, pb0[kt], o01);
          o10 = mfma16k16(v0, pb1[kt], o10);
          o11 = mfma16k16(v1, pb1[kt], o11);
        }
      }
      if (more) {
        *(uint4*)&Ks[buf ^ 1][sk_key][sk_ch] = kr;
        *(uint4*)&Vs[buf ^ 1][sv_d][sv_seg] = vr;
      }
      __syncthreads();
      buf ^= 1;
    }
    // ---- partial epilogue: reduce rs; store bf16 unnormalized O + f32 rs ----
    rs0 += __shfl_xor(rs0, 16);
    rs0 += __shfl_xor(rs0, 32);
    rs1 += __shfl_xor(rs1, 16);
    rs1 += __shfl_xor(rs1, 32);
    __bf16* Op = Opart + (size_t)z * 4096 * 1024;
    size_t row0 = (size_t)(b * 2048 + q_row0);
    size_t row1 = (size_t)(b * 2048 + q_row1);
    bf16x4 w00 = { (__bf16)o00[0], (__bf16)o00[1], (__bf16)o00[2], (__bf16)o00[3] };
    bf16x4 w01 = { (__bf16)o01[0], (__bf16)o01[1], (__bf16)o01[2], (__bf16)o01[3] };
    bf16x4 w10 = { (__bf16)o10[0], (__bf16)o10[1], (__bf16)o10[2], (__bf16)o10[3] };
    bf16x4 w11 = { (__bf16)o11[0], (__bf16)o11[1], (__bf16)o11[2], (__bf16)o11[3] };
    *(bf16x4*)&Op[row0 * 1024 + h * 32 + quad * 4] = w00;
    *(bf16x4*)&Op[row0 * 1024 + h * 32 + 16 + quad * 4] = w01;
    *(bf16x4*)&Op[row1 * 1024 + h * 32 + quad * 4] = w10;
    *(bf16x4*)&Op[row1 * 1024 + h * 32 + 16 + quad * 4] = w11;
    if (quad == 0) {
      size_t ri = ((size_t)(z * 2 + b) * 32 + h) * 2048;
      rspart[ri + q_row0] = rs0;
      rspart[ri + q_row1] = rs1;
    }
    // ---- split-K fixup: second arriver combines this strip for head h ----
    __threadfence();
    __syncthreads();
    if (tid == 0)
      flag_sh = atomicAdd(&flags[(b * 32 + h) * 16 + strip], 1);
    __syncthreads();
    if (flag_sh == 1) {
      __threadfence();  // acquire other z's partials
      const __bf16* P0 = Opart;
      const __bf16* P1 = Opart + 4096ull * 1024;
      const float* r0 = rspart + ((size_t)b * 32 + h) * 2048;
      const float* r1 = rspart + ((size_t)(2 + b) * 32 + h) * 2048;
      int rr = tid >> 2, cc = (tid & 3) * 8;
#pragma unroll
      for (int half = 0; half < 2; half++) {
        int row = strip * 128 + half * 64 + rr;
        size_t off = ((size_t)(b * 2048 + row)) * 1024 + h * 32 + cc;
        bf16x8 a = *(const bf16x8*)&P0[off];
        bf16x8 c = *(const bf16x8*)&P1[off];
        float is = 1.0f / (r0[row] + r1[row]);
        bf16x8 w;
#pragma unroll
        for (int e = 0; e < 8; e++)
          w[e] = (__bf16)(((float)a[e] + (float)c[e]) * is);
        *(bf16x8*)&Ob[off] = w;
      }
    }
  }
}

extern "C" void kernel_launch(void* const* d_in, const int* in_sizes, int n_in,
                              void* d_out, int out_size, void* d_ws, size_t ws_size,
                              hipStream_t stream) {
  const float* hidden = (const float*)d_in[0];
  const int* amask = (const int*)d_in[1];
  const float* Wq = (const float*)d_in[2];
  const float* Wk = (const float*)d_in[3];
  const float* Wv = (const float*)d_in[4];
  const float* Wo = (const float*)d_in[5];
  float* out = (float*)d_out;

  char* p = (char*)d_ws;
  auto carve = [&](size_t elems) {
    __bf16* r = (__bf16*)p;
    p += ((elems * 2 + 255) / 256) * 256;
    return r;
  };
  __bf16* hb = carve(4096ull * 1024);
  __bf16* Wqkvb = carve(1536ull * 1024);
  __bf16* Wob = carve(1024ull * 1024);
  __bf16* QKV = carve(4096ull * 1536);
  __bf16* VT = carve(4096ull * 256);
  __bf16* Ob = carve(4096ull * 1024);
  float* maskb = (float*)carve(8192);          // 4096 f32
  __bf16* Opart = carve(2ull * 4096 * 1024);   // 2 x 8 MB bf16 partials
  float* rspart = (float*)carve(2ull * 2 * 32 * 2048 * 2);
  int* flags = (int*)carve(2048);              // 1024 ints (2*32*16)

  hipMemsetAsync(flags, 0, 1024 * sizeof(int), stream);

  prep<<<6656, 256, 0, stream>>>(hidden, Wq, Wk, Wv, Wo, amask,
                                 hb, Wqkvb, Wob, maskb);

  gemm_qkv<<<dim3(32, 12), 256, 0, stream>>>(hb, Wqkvb, QKV, VT);

  attn<<<dim3(16, 32, 2), 256, 0, stream>>>(QKV, VT, maskb, Opart, rspart,
                                            Ob, flags);

  gemm_out<<<dim3(32, 8), 256, 0, stream>>>(Ob, Wob, out);
}

// Round 12
// 179.451 us; speedup vs baseline: 3.5217x; 3.5217x over previous
//
#include <hip/hip_runtime.h>

typedef __bf16 bf16x8 __attribute__((ext_vector_type(8)));
typedef __bf16 bf16x4 __attribute__((ext_vector_type(4)));
typedef short short4v __attribute__((ext_vector_type(4)));
typedef float f32x4 __attribute__((ext_vector_type(4)));

__device__ __forceinline__ f32x4 mfma16(bf16x8 a, bf16x8 b, f32x4 c) {
  return __builtin_amdgcn_mfma_f32_16x16x32_bf16(a, b, c, 0, 0, 0);
}

// K=16 MFMA: C/D layout == B-operand layout -> S^T frags feed PV directly.
__device__ __forceinline__ f32x4 mfma16k16(bf16x4 a, bf16x4 b, f32x4 c) {
#if __has_builtin(__builtin_amdgcn_mfma_f32_16x16x16bf16_1k)
  short4v as = __builtin_bit_cast(short4v, a);
  short4v bs = __builtin_bit_cast(short4v, b);
  return __builtin_amdgcn_mfma_f32_16x16x16bf16_1k(as, bs, c, 0, 0, 0);
#else
  f32x4 d;
  asm volatile("v_mfma_f32_16x16x16_bf16 %0, %1, %2, %3"
               : "=v"(d)
               : "v"(a), "v"(b), "v"(c));
  return d;
#endif
}

__device__ __forceinline__ float fast_exp2(float x) {
  return __builtin_amdgcn_exp2f(x);  // v_exp_f32 (native exp2)
}

typedef const __attribute__((address_space(1))) void gvoid_t;
typedef __attribute__((address_space(3))) void svoid_t;
__device__ __forceinline__ void lds16(const __bf16* g, __bf16* l) {
  // async 16B/lane global->LDS; dest = wave-uniform base + lane*16
  __builtin_amdgcn_global_load_lds((gvoid_t*)g, (svoid_t*)l, 16, 0, 0);
}

// ------- fused fp32 -> bf16 convert of all inputs (+ mask bias table) -------
__global__ __launch_bounds__(256) void prep(const float* __restrict__ hidden,
                                            const float* __restrict__ Wq,
                                            const float* __restrict__ Wk,
                                            const float* __restrict__ Wv,
                                            const float* __restrict__ Wo,
                                            const int* __restrict__ amask,
                                            __bf16* __restrict__ hb,
                                            __bf16* __restrict__ Wqkvb,
                                            __bf16* __restrict__ Wob,
                                            float* __restrict__ maskb) {
  int idx = blockIdx.x * 256 + threadIdx.x;
  if (idx < 1024) {  // mask bias: 0 -> -1.5e9, 1 -> -16 (static softmax max)
    int4 m = *(const int4*)(amask + idx * 4);
    float4 mb = { m.x ? -16.0f : -1.5e9f, m.y ? -16.0f : -1.5e9f,
                  m.z ? -16.0f : -1.5e9f, m.w ? -16.0f : -1.5e9f };
    *(float4*)(maskb + idx * 4) = mb;
  }
  int q = idx;
  const float* src;
  __bf16* dst;
  if (q < 1048576) {
    src = hidden; dst = hb;
  } else if ((q -= 1048576) < 262144) {
    src = Wq; dst = Wqkvb;
  } else if ((q -= 262144) < 65536) {
    src = Wk; dst = Wqkvb + 1048576;
  } else if ((q -= 65536) < 65536) {
    src = Wv; dst = Wqkvb + 1310720;
  } else {
    q -= 65536;
    src = Wo; dst = Wob;
  }
  float4 v = *(const float4*)(src + (size_t)q * 4);
  bf16x4 o = { (__bf16)v.x, (__bf16)v.y, (__bf16)v.z, (__bf16)v.w };
  *(bf16x4*)(dst + (size_t)q * 4) = o;
}

// ------ QKV GEMM (128x128, lds16 dbuf) with fused RoPE / V-transpose --------
// N=1536. Epilogue: Q/K quadrants get RoPE applied to f32 acc (pairs are
// (acc[i][0],acc[i][1]) and (acc[i][2],acc[i][3]) at d=l16); V quadrants
// write VT[(b*256 + vc)*2048 + s] instead of QKV.
__global__ __launch_bounds__(256) void gemm_qkv(const __bf16* __restrict__ A,
                                                const __bf16* __restrict__ B,
                                                __bf16* __restrict__ QKV,
                                                __bf16* __restrict__ VT) {
  __shared__ __bf16 As[2][128][32];
  __shared__ __bf16 Bs[2][128][32];
  const int m0 = blockIdx.x * 128, n0 = blockIdx.y * 128;
  const int tid = threadIdx.x;
  const int wave = tid >> 6, lane = tid & 63, quad = lane >> 4, l16 = lane & 15;
  const int wr = wave >> 1, wc = wave & 1;
  const int srow = 32 * wave;
  const __bf16* Ag = A + (size_t)(m0 + srow + (lane >> 2)) * 1024 + (lane & 3) * 8;
  const __bf16* Bg = B + (size_t)(n0 + srow + (lane >> 2)) * 1024 + (lane & 3) * 8;
  f32x4 acc[4][4] = {};

  auto stage = [&](int buf, int k0) {
    lds16(Ag + k0, &As[buf][srow][0]);
    lds16(Ag + 16 * 1024 + k0, &As[buf][srow + 16][0]);
    lds16(Bg + k0, &Bs[buf][srow][0]);
    lds16(Bg + 16 * 1024 + k0, &Bs[buf][srow + 16][0]);
  };
  stage(0, 0);
  __syncthreads();
  int buf = 0;
  for (int k0 = 0; k0 < 1024; k0 += 32) {
    if (k0 + 32 < 1024) stage(buf ^ 1, k0 + 32);
    bf16x8 af[4], bfr[4];
#pragma unroll
    for (int i = 0; i < 4; i++)
      af[i] = *(bf16x8*)&As[buf][64 * wr + 16 * i + l16][quad * 8];
#pragma unroll
    for (int j = 0; j < 4; j++)
      bfr[j] = *(bf16x8*)&Bs[buf][64 * wc + 16 * j + l16][quad * 8];
#pragma unroll
    for (int i = 0; i < 4; i++)
#pragma unroll
      for (int j = 0; j < 4; j++) acc[i][j] = mfma16(af[i], bfr[j], acc[i][j]);
    __syncthreads();
    buf ^= 1;
  }
  const int colbase = n0 + 64 * wc;  // wave-uniform; 64-aligned = 2 heads
  if (colbase < 1280) {
    // ---- Q or K quadrant: RoPE on f32 accumulators, then store ----
    float invf = __expf(-(float)l16 * 0.5756462732485114f);  // 10000^(-l16/16)
#pragma unroll
    for (int i = 0; i < 4; i++)
#pragma unroll
      for (int r = 0; r < 4; r++) {
        int row = m0 + 64 * wr + 16 * i + quad * 4 + r;
        float ang = (float)(row & 2047) * invf;
        float sn, cs;
        __sincosf(ang, &sn, &cs);
        float x0 = acc[i][0][r], x1 = acc[i][1][r];
        acc[i][0][r] = x0 * cs - x1 * sn;
        acc[i][1][r] = x1 * cs + x0 * sn;
        float y0 = acc[i][2][r], y1 = acc[i][3][r];
        acc[i][2][r] = y0 * cs - y1 * sn;
        acc[i][3][r] = y1 * cs + y0 * sn;
      }
#pragma unroll
    for (int i = 0; i < 4; i++)
#pragma unroll
      for (int j = 0; j < 4; j++)
#pragma unroll
        for (int r = 0; r < 4; r++) {
          int row = m0 + 64 * wr + 16 * i + quad * 4 + r;
          int col = colbase + 16 * j + l16;
          QKV[(size_t)row * 1536 + col] = (__bf16)acc[i][j][r];
        }
  } else {
    // ---- V quadrant: write transposed VT[(b*256+vc)*2048 + s] ----
#pragma unroll
    for (int i = 0; i < 4; i++)
#pragma unroll
      for (int j = 0; j < 4; j++)
#pragma unroll
        for (int r = 0; r < 4; r++) {
          int row = m0 + 64 * wr + 16 * i + quad * 4 + r;
          int vc = colbase + 16 * j + l16 - 1280;
          int b_ = row >> 11, s = row & 2047;
          VT[((size_t)(b_ * 256 + vc)) * 2048 + s] = (__bf16)acc[i][j][r];
        }
  }
}

// ------ Wo GEMM: plain 128x128 lds16 dbuf, f32 out ------
__global__ __launch_bounds__(256) void gemm_out(const __bf16* __restrict__ A,
                                                const __bf16* __restrict__ B,
                                                float* __restrict__ C) {
  __shared__ __bf16 As[2][128][32];
  __shared__ __bf16 Bs[2][128][32];
  const int m0 = blockIdx.x * 128, n0 = blockIdx.y * 128;
  const int tid = threadIdx.x;
  const int wave = tid >> 6, lane = tid & 63, quad = lane >> 4, l16 = lane & 15;
  const int wr = wave >> 1, wc = wave & 1;
  const int srow = 32 * wave;
  const __bf16* Ag = A + (size_t)(m0 + srow + (lane >> 2)) * 1024 + (lane & 3) * 8;
  const __bf16* Bg = B + (size_t)(n0 + srow + (lane >> 2)) * 1024 + (lane & 3) * 8;
  f32x4 acc[4][4] = {};

  auto stage = [&](int buf, int k0) {
    lds16(Ag + k0, &As[buf][srow][0]);
    lds16(Ag + 16 * 1024 + k0, &As[buf][srow + 16][0]);
    lds16(Bg + k0, &Bs[buf][srow][0]);
    lds16(Bg + 16 * 1024 + k0, &Bs[buf][srow + 16][0]);
  };
  stage(0, 0);
  __syncthreads();
  int buf = 0;
  for (int k0 = 0; k0 < 1024; k0 += 32) {
    if (k0 + 32 < 1024) stage(buf ^ 1, k0 + 32);
    bf16x8 af[4], bfr[4];
#pragma unroll
    for (int i = 0; i < 4; i++)
      af[i] = *(bf16x8*)&As[buf][64 * wr + 16 * i + l16][quad * 8];
#pragma unroll
    for (int j = 0; j < 4; j++)
      bfr[j] = *(bf16x8*)&Bs[buf][64 * wc + 16 * j + l16][quad * 8];
#pragma unroll
    for (int i = 0; i < 4; i++)
#pragma unroll
      for (int j = 0; j < 4; j++) acc[i][j] = mfma16(af[i], bfr[j], acc[i][j]);
    __syncthreads();
    buf ^= 1;
  }
#pragma unroll
  for (int i = 0; i < 4; i++)
#pragma unroll
    for (int j = 0; j < 4; j++)
#pragma unroll
      for (int r = 0; r < 4; r++) {
        int row = m0 + 64 * wr + 16 * i + quad * 4 + r;
        int col = n0 + 64 * wc + 16 * j + l16;
        C[(size_t)row * 1024 + col] = acc[i][j][r];
      }
}

// ------- Flash attention, split-K partials (static max => associative) ------
// Block (xp, z): strips {xp, 15-xp}; z=0 first half of each strip's tiles,
// z=1 second half -> uniform 17 tiles/block. Emits bf16 O-partials + f32 rs.
__global__ __launch_bounds__(256, 4) void attn(const __bf16* __restrict__ QKV,
                                               const __bf16* __restrict__ VT,
                                               const float* __restrict__ maskb,
                                               __bf16* __restrict__ Opart,
                                               float* __restrict__ rspart) {
  __shared__ __bf16 Ks[2][64][40];
  __shared__ __bf16 Vs[2][32][72];
  const int tid = threadIdx.x;
  const int wave = tid >> 6, lane = tid & 63;
  const int quad = lane >> 4, l16 = lane & 15;
  const int b = blockIdx.z, h = blockIdx.y, hkv = h >> 2;
  const int xp = blockIdx.x >> 1, z = blockIdx.x & 1;
  const float SC2 = 0.25503472f;  // (1/sqrt(32)) * log2(e)

  const int sk_key = tid >> 2, sk_ch = (tid & 3) * 8;
  const int sv_d = tid >> 3, sv_seg = (tid & 7) * 8;
  const __bf16* ksrc = QKV + (size_t)(b * 2048 + sk_key) * 1536 + 1024 + hkv * 32 + sk_ch;
  const __bf16* vsrc = VT + ((size_t)(b * 8 + hkv) * 32 + sv_d) * 2048 + sv_seg;
  const float* mrow = maskb + b * 2048;

  for (int sp = 0; sp < 2; sp++) {
    const int strip = sp ? 15 - xp : xp;
    const int t_begin = z ? (strip + 1) : 0;
    const int t_end = z ? (2 * strip + 2) : (strip + 1);
    const int qw = strip * 128 + wave * 32;
    const int q_row0 = qw + l16, q_row1 = qw + 16 + l16;
    const __bf16* qbase = QKV + (size_t)(b * 2048 + qw + l16) * 1536 + h * 32 + quad * 8;
    bf16x8 qf0 = *(const bf16x8*)qbase;
    bf16x8 qf1 = *(const bf16x8*)(qbase + 16 * 1536);

    {  // stage tile t_begin into buffer 0
      uint4 kr = *(const uint4*)(ksrc + (size_t)t_begin * 64 * 1536);
      uint4 vr = *(const uint4*)(vsrc + (size_t)t_begin * 64);
      *(uint4*)&Ks[0][sk_key][sk_ch] = kr;
      *(uint4*)&Vs[0][sv_d][sv_seg] = vr;
    }
    __syncthreads();

    f32x4 o00 = {}, o01 = {}, o10 = {}, o11 = {};
    float rs0 = 0.f, rs1 = 0.f;
    int buf = 0;

    for (int t = t_begin; t < t_end; t++) {
      const int kv0 = t << 6;
      const bool more = (t + 1 < t_end);
      uint4 kr, vr;
      if (more) {
        kr = *(const uint4*)(ksrc + (size_t)(t + 1) * 64 * 1536);
        vr = *(const uint4*)(vsrc + (size_t)(t + 1) * 64);
      }
      if (kv0 <= qw + 31) {  // wave-uniform: any visible key?
        bf16x8 kf[4];
#pragma unroll
        for (int kt = 0; kt < 4; kt++)
          kf[kt] = *(bf16x8*)&Ks[buf][16 * kt + l16][quad * 8];
        f32x4 s0[4], s1[4];
#pragma unroll
        for (int kt = 0; kt < 4; kt++) {
          f32x4 zz = {};
          s0[kt] = mfma16(kf[kt], qf0, zz);
          s1[kt] = mfma16(kf[kt], qf1, zz);
        }
        // ---- static-max softmax -> packed B-operands (registers only) ----
        bf16x4 pb0[4], pb1[4];
        if (kv0 + 63 <= qw) {  // full tile
#pragma unroll
          for (int kt = 0; kt < 4; kt++) {
            const int kb = kv0 + 16 * kt + 4 * quad;
            float4 mb = *(const float4*)(mrow + kb);
#pragma unroll
            for (int r = 0; r < 4; r++) {
              float e0 = fast_exp2(fmaf(s0[kt][r], SC2, (&mb.x)[r]));
              float e1 = fast_exp2(fmaf(s1[kt][r], SC2, (&mb.x)[r]));
              rs0 += e0;
              rs1 += e1;
              pb0[kt][r] = (__bf16)e0;
              pb1[kt][r] = (__bf16)e1;
            }
          }
        } else {  // diagonal tile
#pragma unroll
          for (int kt = 0; kt < 4; kt++) {
            const int kb = kv0 + 16 * kt + 4 * quad;
            float4 mb = *(const float4*)(mrow + kb);
#pragma unroll
            for (int r = 0; r < 4; r++) {
              const int key = kb + r;
              float e0 = fast_exp2(fmaf(s0[kt][r], SC2, (&mb.x)[r]));
              float e1 = fast_exp2(fmaf(s1[kt][r], SC2, (&mb.x)[r]));
              e0 = (key <= q_row0) ? e0 : 0.f;
              e1 = (key <= q_row1) ? e1 : 0.f;
              rs0 += e0;
              rs1 += e1;
              pb0[kt][r] = (__bf16)e0;
              pb1[kt][r] = (__bf16)e1;
            }
          }
        }
        // ---- PV via K=16 MFMA: A = V^T frags (8B LDS reads), B = pb regs ---
#pragma unroll
        for (int kt = 0; kt < 4; kt++) {
          bf16x4 v0 = *(bf16x4*)&Vs[buf][l16][16 * kt + 4 * quad];
          bf16x4 v1 = *(bf16x4*)&Vs[buf][16 + l16][16 * kt + 4 * quad];
          o00 = mfma16k16(v0, pb0[kt], o00);
          o01 = mfma16k16(v1, pb0[kt], o01);
          o10 = mfma16k16(v0, pb1[kt], o10);
          o11 = mfma16k16(v1, pb1[kt], o11);
        }
      }
      if (more) {
        *(uint4*)&Ks[buf ^ 1][sk_key][sk_ch] = kr;
        *(uint4*)&Vs[buf ^ 1][sv_d][sv_seg] = vr;
      }
      __syncthreads();
      buf ^= 1;
    }
    // ---- partial epilogue: reduce rs; store bf16 unnormalized O + f32 rs ----
    rs0 += __shfl_xor(rs0, 16);
    rs0 += __shfl_xor(rs0, 32);
    rs1 += __shfl_xor(rs1, 16);
    rs1 += __shfl_xor(rs1, 32);
    __bf16* Op = Opart + (size_t)z * 4096 * 1024;
    size_t row0 = (size_t)(b * 2048 + q_row0);
    size_t row1 = (size_t)(b * 2048 + q_row1);
    bf16x4 w00 = { (__bf16)o00[0], (__bf16)o00[1], (__bf16)o00[2], (__bf16)o00[3] };
    bf16x4 w01 = { (__bf16)o01[0], (__bf16)o01[1], (__bf16)o01[2], (__bf16)o01[3] };
    bf16x4 w10 = { (__bf16)o10[0], (__bf16)o10[1], (__bf16)o10[2], (__bf16)o10[3] };
    bf16x4 w11 = { (__bf16)o11[0], (__bf16)o11[1], (__bf16)o11[2], (__bf16)o11[3] };
    *(bf16x4*)&Op[row0 * 1024 + h * 32 + quad * 4] = w00;
    *(bf16x4*)&Op[row0 * 1024 + h * 32 + 16 + quad * 4] = w01;
    *(bf16x4*)&Op[row1 * 1024 + h * 32 + quad * 4] = w10;
    *(bf16x4*)&Op[row1 * 1024 + h * 32 + 16 + quad * 4] = w11;
    if (quad == 0) {
      size_t ri = ((size_t)(z * 2 + b) * 32 + h) * 2048;
      rspart[ri + q_row0] = rs0;
      rspart[ri + q_row1] = rs1;
    }
  }
}

// ---- combine partials: Ob = (O0 + O1) / (rs0 + rs1), bf16 ----
__global__ __launch_bounds__(256) void combine(const __bf16* __restrict__ Opart,
                                               const float* __restrict__ rspart,
                                               __bf16* __restrict__ Ob) {
  int idx = blockIdx.x * 256 + threadIdx.x;  // 524288: (row, 8-elem group)
  int row = idx >> 7, g = idx & 127;
  int b = row >> 11, q = row & 2047, h = g >> 2;
  size_t off = (size_t)row * 1024 + g * 8;
  bf16x8 a = *(const bf16x8*)(Opart + off);
  bf16x8 c = *(const bf16x8*)(Opart + 4194304 + off);
  size_t ri = ((size_t)b * 32 + h) * 2048 + q;
  float inv = 1.0f / (rspart[ri] + rspart[2 * 65536 + ri]);
  bf16x8 w;
#pragma unroll
  for (int e = 0; e < 8; e++)
    w[e] = (__bf16)(((float)a[e] + (float)c[e]) * inv);
  *(bf16x8*)&Ob[off] = w;
}

extern "C" void kernel_launch(void* const* d_in, const int* in_sizes, int n_in,
                              void* d_out, int out_size, void* d_ws, size_t ws_size,
                              hipStream_t stream) {
  const float* hidden = (const float*)d_in[0];
  const int* amask = (const int*)d_in[1];
  const float* Wq = (const float*)d_in[2];
  const float* Wk = (const float*)d_in[3];
  const float* Wv = (const float*)d_in[4];
  const float* Wo = (const float*)d_in[5];
  float* out = (float*)d_out;

  char* p = (char*)d_ws;
  auto carve = [&](size_t elems) {
    __bf16* r = (__bf16*)p;
    p += ((elems * 2 + 255) / 256) * 256;
    return r;
  };
  __bf16* hb = carve(4096ull * 1024);
  __bf16* Wqkvb = carve(1536ull * 1024);
  __bf16* Wob = carve(1024ull * 1024);
  __bf16* QKV = carve(4096ull * 1536);
  __bf16* VT = carve(4096ull * 256);
  __bf16* Ob = carve(4096ull * 1024);
  float* maskb = (float*)carve(8192);          // 4096 f32
  __bf16* Opart = carve(2ull * 4096 * 1024);   // 2 x 8 MB bf16 partials
  float* rspart = (float*)carve(2ull * 2 * 32 * 2048 * 2);

  prep<<<6656, 256, 0, stream>>>(hidden, Wq, Wk, Wv, Wo, amask,
                                 hb, Wqkvb, Wob, maskb);

  gemm_qkv<<<dim3(32, 12), 256, 0, stream>>>(hb, Wqkvb, QKV, VT);

  attn<<<dim3(16, 32, 2), 256, 0, stream>>>(QKV, VT, maskb, Opart, rspart);

  combine<<<2048, 256, 0, stream>>>(Opart, rspart, Ob);

  gemm_out<<<dim3(32, 8), 256, 0, stream>>>(Ob, Wob, out);
}